// Round 1
// baseline (478.563 us; speedup 1.0000x reference)
//
#include <hip/hip_runtime.h>
#include <math.h>

// Problem constants (fixed by reference)
namespace {
constexpr int NB = 4;       // batch
constexpr int NN = 2048;    // sequence
constexpr int FD = 1024;    // feature dim
constexpr int DE = 128;     // energy dim
constexpr int BN = NB * NN; // 8192 rows total

// workspace layout in floats
constexpr size_t BASE_OFF = 0;                                // [B][N][N]
constexpr size_t Q_OFF  = (size_t)NB * NN * NN;               // 16,777,216
constexpr size_t K_OFF  = Q_OFF + (size_t)BN * DE;            // +1,048,576
constexpr size_t M_OFF  = K_OFF + (size_t)BN * DE;            // row max  [BN]
constexpr size_t S_OFF  = M_OFF + BN;                         // row 1/sum [BN]
constexpr size_t C_OFF  = S_OFF + BN;                         // charges: 5 slots of [BN]
constexpr size_t R_OFF  = C_OFF + (size_t)5 * BN;             // received [BN]
}

// ---------------------------------------------------------------------------
// K0: Q = F @ Wq, K = F @ Wk.  F:[BN,1024], W:[1024,128].
// Block = 256 thr, tile 32 rows x 128 cols, K-chunks of 32.
__global__ __launch_bounds__(256) void qk_gemm(
        const float* __restrict__ feat, const float* __restrict__ Wq,
        const float* __restrict__ Wk, float* __restrict__ Q, float* __restrict__ K) {
    __shared__ float fs[32 * 36];     // 32 rows x 32 f, stride 36 (16B-aligned, bank-shifted)
    __shared__ float wqs[32 * 128];   // [f][e]
    __shared__ float wks[32 * 128];
    const int tid = threadIdx.x;
    const int row0 = blockIdx.x * 32;
    const int rg = tid >> 5;          // 0..7 -> rows rg*4..rg*4+3
    const int eg = tid & 31;          // 0..31 -> e = eg*4..eg*4+3

    float accQ[4][4] = {{0.f}}, accK[4][4] = {{0.f}};

    for (int f0 = 0; f0 < FD; f0 += 32) {
        {   // feat tile: 1024 floats = 256 float4
            int r = tid >> 3, fq = (tid & 7) << 2;
            float4 v = *(const float4*)&feat[(size_t)(row0 + r) * FD + f0 + fq];
            *(float4*)&fs[r * 36 + fq] = v;
        }
        #pragma unroll
        for (int k = 0; k < 4; ++k) {  // W tiles: 4096 floats each = 1024 float4
            int idx = tid + 256 * k;
            int fr = idx >> 5, eq = (idx & 31) << 2;
            *(float4*)&wqs[fr * 128 + eq] = *(const float4*)&Wq[(size_t)(f0 + fr) * DE + eq];
            *(float4*)&wks[fr * 128 + eq] = *(const float4*)&Wk[(size_t)(f0 + fr) * DE + eq];
        }
        __syncthreads();
        #pragma unroll 8
        for (int f = 0; f < 32; ++f) {
            float4 wq = *(const float4*)&wqs[f * 128 + (eg << 2)];
            float4 wk = *(const float4*)&wks[f * 128 + (eg << 2)];
            #pragma unroll
            for (int rr = 0; rr < 4; ++rr) {
                float fv = fs[(rg * 4 + rr) * 36 + f];
                accQ[rr][0] += fv * wq.x; accQ[rr][1] += fv * wq.y;
                accQ[rr][2] += fv * wq.z; accQ[rr][3] += fv * wq.w;
                accK[rr][0] += fv * wk.x; accK[rr][1] += fv * wk.y;
                accK[rr][2] += fv * wk.z; accK[rr][3] += fv * wk.w;
            }
        }
        __syncthreads();
    }
    #pragma unroll
    for (int rr = 0; rr < 4; ++rr) {
        int row = row0 + rg * 4 + rr;
        float4 vq = {accQ[rr][0], accQ[rr][1], accQ[rr][2], accQ[rr][3]};
        float4 vk = {accK[rr][0], accK[rr][1], accK[rr][2], accK[rr][3]};
        *(float4*)&Q[(size_t)row * DE + (eg << 2)] = vq;
        *(float4*)&K[(size_t)row * DE + (eg << 2)] = vk;
    }
}

// ---------------------------------------------------------------------------
// Kc: c0 = sigmoid(F @ cw + cb).  One wave per row.
__global__ __launch_bounds__(256) void charge_init(
        const float* __restrict__ feat, const float* __restrict__ cw,
        const float* __restrict__ cb, float* __restrict__ c0) {
    const int wave = threadIdx.x >> 6, lane = threadIdx.x & 63;
    const int r = blockIdx.x * 4 + wave;   // grid 2048 -> 8192 rows
    const float* fr = feat + (size_t)r * FD;
    float s = 0.f;
    #pragma unroll
    for (int k = 0; k < 16; ++k) { int f = lane + 64 * k; s += fr[f] * cw[f]; }
    for (int off = 32; off > 0; off >>= 1) s += __shfl_xor(s, off);
    if (lane == 0) {
        float x = s + cb[0];
        c0[r] = 1.f / (1.f + __expf(-x));
    }
}

// ---------------------------------------------------------------------------
// K1: base[b,i,j] = (Q_i . K_j)/sqrt(128) + ls/max(|i-j|,1).
// 128x128 tile per block, 256 thr, 8x8 per thread, K-chunks of 64.
__global__ __launch_bounds__(256) void base_kernel(
        const float* __restrict__ Q, const float* __restrict__ K,
        const float* __restrict__ d_ls, float* __restrict__ base) {
    __shared__ float qs[128 * 68];   // stride 68 words: 16B aligned, banks +4/row
    __shared__ float ks[128 * 68];
    const int tid = threadIdx.x;
    const int tx = tid & 15, ty = tid >> 4;
    const int b = blockIdx.z;
    const int i0 = blockIdx.y * 128, j0 = blockIdx.x * 128;
    const float* Qb = Q + (size_t)b * NN * DE;
    const float* Kb = K + (size_t)b * NN * DE;

    float acc[8][8] = {{0.f}};

    for (int f0 = 0; f0 < DE; f0 += 64) {
        #pragma unroll
        for (int k = 0; k < 8; ++k) {   // 2048 float4 per tile, 8/thread
            int idx = tid + 256 * k;
            int r = idx >> 4, fq = (idx & 15) << 2;
            *(float4*)&qs[r * 68 + fq] = *(const float4*)&Qb[(size_t)(i0 + r) * DE + f0 + fq];
            *(float4*)&ks[r * 68 + fq] = *(const float4*)&Kb[(size_t)(j0 + r) * DE + f0 + fq];
        }
        __syncthreads();
        #pragma unroll 4
        for (int f = 0; f < 64; ++f) {
            float q[8], kk[8];
            #pragma unroll
            for (int d = 0; d < 8; ++d) q[d]  = qs[(ty + 16 * d) * 68 + f];
            #pragma unroll
            for (int d = 0; d < 8; ++d) kk[d] = ks[(tx + 16 * d) * 68 + f];
            #pragma unroll
            for (int di = 0; di < 8; ++di)
                #pragma unroll
                for (int dj = 0; dj < 8; ++dj)
                    acc[di][dj] += q[di] * kk[dj];
        }
        __syncthreads();
    }
    const float ls = d_ls[0];
    const float rs = 0.08838834764831845f;  // 1/sqrt(128)
    #pragma unroll
    for (int di = 0; di < 8; ++di) {
        int i = i0 + ty + 16 * di;
        #pragma unroll
        for (int dj = 0; dj < 8; ++dj) {
            int j = j0 + tx + 16 * dj;
            float dist = fmaxf(fabsf((float)(i - j)), 1.0f);
            base[((size_t)b * NN + i) * NN + j] = acc[di][dj] * rs + ls / dist;
        }
    }
}

// ---------------------------------------------------------------------------
// K2: one block per row r. logits = base * (1 + ss * sum_u c_u[i] c_u[j]).
// mode 0: write m[r], 1/s[r], zero received[r].  mode 1: write softmax row to out.
template <int WRITE_OUT>
__global__ __launch_bounds__(256) void row_pass(
        const float* __restrict__ base, const float* __restrict__ charge,
        int t, const float* __restrict__ d_ss,
        float* __restrict__ m_out, float* __restrict__ invs_out,
        float* __restrict__ received, float* __restrict__ out) {
    const int r = blockIdx.x;          // 0..BN-1
    const int b = r >> 11;
    const int tid = threadIdx.x;
    const float* row = base + (size_t)r * NN;
    const float ss = d_ss[0];

    float ci[4];
    for (int u = 0; u < t; ++u) ci[u] = charge[(size_t)(u + 1) * BN + r] * ss;

    float x[8];
    float mx = -1e30f;
    #pragma unroll
    for (int k = 0; k < 2; ++k) {
        int j = (tid << 2) + (k << 10);
        float4 bv = *(const float4*)&row[j];
        float m0 = 1.f, m1 = 1.f, m2 = 1.f, m3 = 1.f;
        for (int u = 0; u < t; ++u) {
            const float* cu = charge + (size_t)(u + 1) * BN + ((size_t)b << 11);
            float4 cj = *(const float4*)&cu[j];
            m0 += ci[u] * cj.x; m1 += ci[u] * cj.y;
            m2 += ci[u] * cj.z; m3 += ci[u] * cj.w;
        }
        x[k * 4 + 0] = bv.x * m0; x[k * 4 + 1] = bv.y * m1;
        x[k * 4 + 2] = bv.z * m2; x[k * 4 + 3] = bv.w * m3;
        mx = fmaxf(mx, fmaxf(fmaxf(x[k * 4], x[k * 4 + 1]), fmaxf(x[k * 4 + 2], x[k * 4 + 3])));
    }
    for (int off = 32; off > 0; off >>= 1) mx = fmaxf(mx, __shfl_xor(mx, off));
    __shared__ float redm[4], reds[4];
    const int wave = tid >> 6, lane = tid & 63;
    if (lane == 0) redm[wave] = mx;
    __syncthreads();
    mx = fmaxf(fmaxf(redm[0], redm[1]), fmaxf(redm[2], redm[3]));

    float e[8], se = 0.f;
    #pragma unroll
    for (int q = 0; q < 8; ++q) { e[q] = __expf(x[q] - mx); se += e[q]; }
    for (int off = 32; off > 0; off >>= 1) se += __shfl_xor(se, off);
    if (lane == 0) reds[wave] = se;
    __syncthreads();
    se = reds[0] + reds[1] + reds[2] + reds[3];
    float inv = 1.0f / se;

    if (WRITE_OUT) {
        #pragma unroll
        for (int k = 0; k < 2; ++k) {
            int j = (tid << 2) + (k << 10);
            float4 o = {e[k * 4 + 0] * inv, e[k * 4 + 1] * inv,
                        e[k * 4 + 2] * inv, e[k * 4 + 3] * inv};
            *(float4*)&out[(size_t)r * NN + j] = o;
        }
    } else {
        if (tid == 0) { m_out[r] = mx; invs_out[r] = inv; received[r] = 0.f; }
    }
}

// ---------------------------------------------------------------------------
// K3: received[b,j] += sum_i exp(logit[i,j]-m_i)/s_i over a 128-row slab.
__global__ __launch_bounds__(256) void col_pass(
        const float* __restrict__ base, const float* __restrict__ charge,
        int t, const float* __restrict__ d_ss,
        const float* __restrict__ m_arr, const float* __restrict__ invs_arr,
        float* __restrict__ received) {
    const int b = blockIdx.z;
    const int j = blockIdx.x * 256 + threadIdx.x;
    const int i0 = blockIdx.y * 128;
    const float ss = d_ss[0];

    float cj[4];
    for (int u = 0; u < t; ++u)
        cj[u] = charge[(size_t)(u + 1) * BN + ((size_t)b << 11) + j] * ss;

    const float* bp = base + ((size_t)b * NN + i0) * NN + j;
    float acc = 0.f;
    for (int ii = 0; ii < 128; ++ii) {
        int ri = ((size_t)b << 11) + i0 + ii;
        float bv = bp[(size_t)ii * NN];
        float mult = 1.f;
        for (int u = 0; u < t; ++u)
            mult += cj[u] * charge[(size_t)(u + 1) * BN + ri];
        float x = bv * mult;
        acc += __expf(x - m_arr[ri]) * invs_arr[ri];
    }
    atomicAdd(&received[((size_t)b << 11) + j], acc);
}

// ---------------------------------------------------------------------------
// K4: c_{t+1} = c_t * (1 - decay * sigmoid(received - 1))
__global__ __launch_bounds__(256) void charge_update(
        const float* __restrict__ received, const float* __restrict__ d_decay,
        const float* __restrict__ c_prev, float* __restrict__ c_next) {
    const int r = blockIdx.x * 256 + threadIdx.x;   // 8192
    float recv = received[r];
    float sg = 1.f / (1.f + __expf(1.f - recv));
    c_next[r] = c_prev[r] * (1.f - d_decay[0] * sg);
}

// ---------------------------------------------------------------------------
extern "C" void kernel_launch(void* const* d_in, const int* in_sizes, int n_in,
                              void* d_out, int out_size, void* d_ws, size_t ws_size,
                              hipStream_t stream) {
    const float* feat  = (const float*)d_in[0];
    const float* Wq    = (const float*)d_in[1];
    const float* Wk    = (const float*)d_in[2];
    const float* cw    = (const float*)d_in[3];
    const float* cb    = (const float*)d_in[4];
    const float* ls    = (const float*)d_in[5];
    const float* ssp   = (const float*)d_in[6];
    const float* decay = (const float*)d_in[7];

    float* ws     = (float*)d_ws;
    float* base   = ws + BASE_OFF;
    float* Qp     = ws + Q_OFF;
    float* Kp     = ws + K_OFF;
    float* m_arr  = ws + M_OFF;
    float* invs   = ws + S_OFF;
    float* charge = ws + C_OFF;   // 5 x [BN]; slot 0 = initial
    float* recv   = ws + R_OFF;
    float* out    = (float*)d_out;

    qk_gemm<<<BN / 32, 256, 0, stream>>>(feat, Wq, Wk, Qp, Kp);
    charge_init<<<BN / 4, 256, 0, stream>>>(feat, cw, cb, charge);
    base_kernel<<<dim3(NN / 128, NN / 128, NB), 256, 0, stream>>>(Qp, Kp, ls, base);

    for (int t = 0; t < 4; ++t) {
        row_pass<0><<<BN, 256, 0, stream>>>(base, charge, t, ssp, m_arr, invs, recv, nullptr);
        col_pass<<<dim3(NN / 256, NN / 128, NB), 256, 0, stream>>>(
            base, charge, t, ssp, m_arr, invs, recv);
        charge_update<<<BN / 256, 256, 0, stream>>>(
            recv, decay, charge + (size_t)t * BN, charge + (size_t)(t + 1) * BN);
    }
    row_pass<1><<<BN, 256, 0, stream>>>(base, charge, 4, ssp, m_arr, invs, recv, out);
}

// Round 2
// 441.637 us; speedup vs baseline: 1.0836x; 1.0836x over previous
//
#include <hip/hip_runtime.h>
#include <math.h>

// Problem constants (fixed by reference)
namespace {
constexpr int NB = 4;       // batch
constexpr int NN = 2048;    // sequence
constexpr int FD = 1024;    // feature dim
constexpr int DE = 128;     // energy dim
constexpr int BN = NB * NN; // 8192 rows total

// workspace layout in floats
constexpr size_t BASE_OFF = 0;                                // [B][N][N] (also reused for qk partials)
constexpr size_t Q_OFF  = (size_t)NB * NN * NN;               // 16,777,216
constexpr size_t K_OFF  = Q_OFF + (size_t)BN * DE;            // +1,048,576
constexpr size_t M_OFF  = K_OFF + (size_t)BN * DE;            // row max  [BN]
constexpr size_t S_OFF  = M_OFF + BN;                         // row 1/sum [BN]
constexpr size_t C_OFF  = S_OFF + BN;                         // charges: 5 slots of [BN]
constexpr size_t R_OFF  = C_OFF + (size_t)5 * BN;             // received [BN]
}

// ---------------------------------------------------------------------------
// K0: partial Q/K GEMM.  F:[BN,1024], W:[1024,128].
// Grid (256, 4): blockIdx.x = 32-row tile, blockIdx.y = K-chunk of 256 feats.
// Partials written to part[ chunk ][BN][DE] for Q and K (in base region).
__global__ __launch_bounds__(256) void qk_gemm(
        const float* __restrict__ feat, const float* __restrict__ Wq,
        const float* __restrict__ Wk, float* __restrict__ partQ, float* __restrict__ partK) {
    __shared__ float fs[32 * 36];     // 32 rows x 32 f, stride 36
    __shared__ float wqs[32 * 128];   // [f][e]
    __shared__ float wks[32 * 128];
    const int tid = threadIdx.x;
    const int row0 = blockIdx.x * 32;
    const int kc = blockIdx.y;        // K chunk 0..3
    const int rg = tid >> 5;          // 0..7 -> rows rg*4..rg*4+3
    const int eg = tid & 31;          // 0..31 -> e = eg*4..eg*4+3

    float accQ[4][4] = {{0.f}}, accK[4][4] = {{0.f}};

    const int fbeg = kc * 256, fend = fbeg + 256;
    for (int f0 = fbeg; f0 < fend; f0 += 32) {
        {   // feat tile: 1024 floats = 256 float4
            int r = tid >> 3, fq = (tid & 7) << 2;
            float4 v = *(const float4*)&feat[(size_t)(row0 + r) * FD + f0 + fq];
            *(float4*)&fs[r * 36 + fq] = v;
        }
        #pragma unroll
        for (int k = 0; k < 4; ++k) {  // W tiles: 4096 floats each = 1024 float4
            int idx = tid + 256 * k;
            int fr = idx >> 5, eq = (idx & 31) << 2;
            *(float4*)&wqs[fr * 128 + eq] = *(const float4*)&Wq[(size_t)(f0 + fr) * DE + eq];
            *(float4*)&wks[fr * 128 + eq] = *(const float4*)&Wk[(size_t)(f0 + fr) * DE + eq];
        }
        __syncthreads();
        #pragma unroll 8
        for (int f = 0; f < 32; ++f) {
            float4 wq = *(const float4*)&wqs[f * 128 + (eg << 2)];
            float4 wk = *(const float4*)&wks[f * 128 + (eg << 2)];
            #pragma unroll
            for (int rr = 0; rr < 4; ++rr) {
                float fv = fs[(rg * 4 + rr) * 36 + f];
                accQ[rr][0] += fv * wq.x; accQ[rr][1] += fv * wq.y;
                accQ[rr][2] += fv * wq.z; accQ[rr][3] += fv * wq.w;
                accK[rr][0] += fv * wk.x; accK[rr][1] += fv * wk.y;
                accK[rr][2] += fv * wk.z; accK[rr][3] += fv * wk.w;
            }
        }
        __syncthreads();
    }
    float* pq = partQ + (size_t)kc * BN * DE;
    float* pk = partK + (size_t)kc * BN * DE;
    #pragma unroll
    for (int rr = 0; rr < 4; ++rr) {
        int row = row0 + rg * 4 + rr;
        float4 vq = {accQ[rr][0], accQ[rr][1], accQ[rr][2], accQ[rr][3]};
        float4 vk = {accK[rr][0], accK[rr][1], accK[rr][2], accK[rr][3]};
        *(float4*)&pq[(size_t)row * DE + (eg << 2)] = vq;
        *(float4*)&pk[(size_t)row * DE + (eg << 2)] = vk;
    }
}

// Sum the 4 K-chunk partials (deterministic).
__global__ __launch_bounds__(256) void qk_reduce(
        const float* __restrict__ partQ, const float* __restrict__ partK,
        float* __restrict__ Q, float* __restrict__ K) {
    const size_t idx = ((size_t)blockIdx.x * 256 + threadIdx.x) << 2;  // float4 index
    float4 q = {0.f, 0.f, 0.f, 0.f}, k = {0.f, 0.f, 0.f, 0.f};
    #pragma unroll
    for (int c = 0; c < 4; ++c) {
        float4 a = *(const float4*)&partQ[(size_t)c * BN * DE + idx];
        float4 b = *(const float4*)&partK[(size_t)c * BN * DE + idx];
        q.x += a.x; q.y += a.y; q.z += a.z; q.w += a.w;
        k.x += b.x; k.y += b.y; k.z += b.z; k.w += b.w;
    }
    *(float4*)&Q[idx] = q;
    *(float4*)&K[idx] = k;
}

// ---------------------------------------------------------------------------
// Kc: c0 = sigmoid(F @ cw + cb).  One wave per row.
__global__ __launch_bounds__(256) void charge_init(
        const float* __restrict__ feat, const float* __restrict__ cw,
        const float* __restrict__ cb, float* __restrict__ c0) {
    const int wave = threadIdx.x >> 6, lane = threadIdx.x & 63;
    const int r = blockIdx.x * 4 + wave;   // grid 2048 -> 8192 rows
    const float* fr = feat + (size_t)r * FD;
    float s = 0.f;
    #pragma unroll
    for (int k = 0; k < 16; ++k) { int f = lane + 64 * k; s += fr[f] * cw[f]; }
    for (int off = 32; off > 0; off >>= 1) s += __shfl_xor(s, off);
    if (lane == 0) {
        float x = s + cb[0];
        c0[r] = 1.f / (1.f + __expf(-x));
    }
}

// ---------------------------------------------------------------------------
// K1: base[b,i,j] = (Q_i . K_j)/sqrt(128) + ls/max(|i-j|,1).
// 128x128 tile per block, 256 thr, 8x8 per thread (contiguous rows/cols),
// LDS tiles stored transposed [f][row] (stride 132) -> ds_read_b128 fragments.
// f-chunk = 32 -> LDS 33.8 KB -> 4 blocks/CU.
__global__ __launch_bounds__(256, 4) void base_kernel(
        const float* __restrict__ Q, const float* __restrict__ K,
        const float* __restrict__ d_ls, float* __restrict__ base) {
    __shared__ float qs[32 * 132];   // [f][row], stride 132 (16B aligned)
    __shared__ float ks[32 * 132];
    const int tid = threadIdx.x;
    const int tx = tid & 15, ty = tid >> 4;
    const int b = blockIdx.z;
    const int i0 = blockIdx.y * 128, j0 = blockIdx.x * 128;
    const float* Qb = Q + (size_t)b * NN * DE;
    const float* Kb = K + (size_t)b * NN * DE;

    float acc[8][8] = {{0.f}};

    for (int f0 = 0; f0 < DE; f0 += 32) {
        #pragma unroll
        for (int k = 0; k < 4; ++k) {   // 1024 float4 per tile, 4/thread
            int idx = tid + 256 * k;
            int r = idx >> 3, fq = (idx & 7) << 2;
            float4 vq = *(const float4*)&Qb[(size_t)(i0 + r) * DE + f0 + fq];
            float4 vk = *(const float4*)&Kb[(size_t)(j0 + r) * DE + f0 + fq];
            qs[(fq + 0) * 132 + r] = vq.x; qs[(fq + 1) * 132 + r] = vq.y;
            qs[(fq + 2) * 132 + r] = vq.z; qs[(fq + 3) * 132 + r] = vq.w;
            ks[(fq + 0) * 132 + r] = vk.x; ks[(fq + 1) * 132 + r] = vk.y;
            ks[(fq + 2) * 132 + r] = vk.z; ks[(fq + 3) * 132 + r] = vk.w;
        }
        __syncthreads();
        #pragma unroll 8
        for (int f = 0; f < 32; ++f) {
            float4 qa = *(const float4*)&qs[f * 132 + ty * 8];
            float4 qb = *(const float4*)&qs[f * 132 + ty * 8 + 4];
            float4 ka = *(const float4*)&ks[f * 132 + tx * 8];
            float4 kb = *(const float4*)&ks[f * 132 + tx * 8 + 4];
            float q[8] = {qa.x, qa.y, qa.z, qa.w, qb.x, qb.y, qb.z, qb.w};
            float kk[8] = {ka.x, ka.y, ka.z, ka.w, kb.x, kb.y, kb.z, kb.w};
            #pragma unroll
            for (int di = 0; di < 8; ++di)
                #pragma unroll
                for (int dj = 0; dj < 8; ++dj)
                    acc[di][dj] += q[di] * kk[dj];
        }
        __syncthreads();
    }
    const float ls = d_ls[0];
    const float rs = 0.08838834764831845f;  // 1/sqrt(128)
    #pragma unroll
    for (int di = 0; di < 8; ++di) {
        int i = i0 + ty * 8 + di;
        float* brow = base + ((size_t)b * NN + i) * NN;
        float o[8];
        #pragma unroll
        for (int dj = 0; dj < 8; ++dj) {
            int j = j0 + tx * 8 + dj;
            float dist = fmaxf(fabsf((float)(i - j)), 1.0f);
            o[dj] = acc[di][dj] * rs + ls / dist;
        }
        *(float4*)&brow[j0 + tx * 8]     = *(float4*)&o[0];
        *(float4*)&brow[j0 + tx * 8 + 4] = *(float4*)&o[4];
    }
}

// ---------------------------------------------------------------------------
// K2: one block per row r. logits = base * (1 + ss * sum_u c_u[i] c_u[j]).
// mode 0: write m[r], 1/s[r], zero received[r].  mode 1: write softmax row to out.
template <int WRITE_OUT>
__global__ __launch_bounds__(256) void row_pass(
        const float* __restrict__ base, const float* __restrict__ charge,
        int t, const float* __restrict__ d_ss,
        float* __restrict__ m_out, float* __restrict__ invs_out,
        float* __restrict__ received, float* __restrict__ out) {
    const int r = blockIdx.x;          // 0..BN-1
    const int b = r >> 11;
    const int tid = threadIdx.x;
    const float* row = base + (size_t)r * NN;
    const float ss = d_ss[0];

    float ci[4];
    for (int u = 0; u < t; ++u) ci[u] = charge[(size_t)(u + 1) * BN + r] * ss;

    float x[8];
    float mx = -1e30f;
    #pragma unroll
    for (int k = 0; k < 2; ++k) {
        int j = (tid << 2) + (k << 10);
        float4 bv = *(const float4*)&row[j];
        float m0 = 1.f, m1 = 1.f, m2 = 1.f, m3 = 1.f;
        for (int u = 0; u < t; ++u) {
            const float* cu = charge + (size_t)(u + 1) * BN + ((size_t)b << 11);
            float4 cj = *(const float4*)&cu[j];
            m0 += ci[u] * cj.x; m1 += ci[u] * cj.y;
            m2 += ci[u] * cj.z; m3 += ci[u] * cj.w;
        }
        x[k * 4 + 0] = bv.x * m0; x[k * 4 + 1] = bv.y * m1;
        x[k * 4 + 2] = bv.z * m2; x[k * 4 + 3] = bv.w * m3;
        mx = fmaxf(mx, fmaxf(fmaxf(x[k * 4], x[k * 4 + 1]), fmaxf(x[k * 4 + 2], x[k * 4 + 3])));
    }
    for (int off = 32; off > 0; off >>= 1) mx = fmaxf(mx, __shfl_xor(mx, off));
    __shared__ float redm[4], reds[4];
    const int wave = tid >> 6, lane = tid & 63;
    if (lane == 0) redm[wave] = mx;
    __syncthreads();
    mx = fmaxf(fmaxf(redm[0], redm[1]), fmaxf(redm[2], redm[3]));

    float e[8], se = 0.f;
    #pragma unroll
    for (int q = 0; q < 8; ++q) { e[q] = __expf(x[q] - mx); se += e[q]; }
    for (int off = 32; off > 0; off >>= 1) se += __shfl_xor(se, off);
    if (lane == 0) reds[wave] = se;
    __syncthreads();
    se = reds[0] + reds[1] + reds[2] + reds[3];
    float inv = 1.0f / se;

    if (WRITE_OUT) {
        #pragma unroll
        for (int k = 0; k < 2; ++k) {
            int j = (tid << 2) + (k << 10);
            float4 o = {e[k * 4 + 0] * inv, e[k * 4 + 1] * inv,
                        e[k * 4 + 2] * inv, e[k * 4 + 3] * inv};
            *(float4*)&out[(size_t)r * NN + j] = o;
        }
    } else {
        if (tid == 0) { m_out[r] = mx; invs_out[r] = inv; received[r] = 0.f; }
    }
}

// ---------------------------------------------------------------------------
// K3: received[b,j] += sum_i exp(logit[i,j]-m_i)/s_i over a 128-row slab.
__global__ __launch_bounds__(256) void col_pass(
        const float* __restrict__ base, const float* __restrict__ charge,
        int t, const float* __restrict__ d_ss,
        const float* __restrict__ m_arr, const float* __restrict__ invs_arr,
        float* __restrict__ received) {
    const int b = blockIdx.z;
    const int j = blockIdx.x * 256 + threadIdx.x;
    const int i0 = blockIdx.y * 128;
    const float ss = d_ss[0];

    float cj[4];
    for (int u = 0; u < t; ++u)
        cj[u] = charge[(size_t)(u + 1) * BN + ((size_t)b << 11) + j] * ss;

    const float* bp = base + ((size_t)b * NN + i0) * NN + j;
    float acc = 0.f;
    for (int ii = 0; ii < 128; ++ii) {
        int ri = ((size_t)b << 11) + i0 + ii;
        float bv = bp[(size_t)ii * NN];
        float mult = 1.f;
        for (int u = 0; u < t; ++u)
            mult += cj[u] * charge[(size_t)(u + 1) * BN + ri];
        float x = bv * mult;
        acc += __expf(x - m_arr[ri]) * invs_arr[ri];
    }
    atomicAdd(&received[((size_t)b << 11) + j], acc);
}

// ---------------------------------------------------------------------------
// K4: c_{t+1} = c_t * (1 - decay * sigmoid(received - 1))
__global__ __launch_bounds__(256) void charge_update(
        const float* __restrict__ received, const float* __restrict__ d_decay,
        const float* __restrict__ c_prev, float* __restrict__ c_next) {
    const int r = blockIdx.x * 256 + threadIdx.x;   // 8192
    float recv = received[r];
    float sg = 1.f / (1.f + __expf(1.f - recv));
    c_next[r] = c_prev[r] * (1.f - d_decay[0] * sg);
}

// ---------------------------------------------------------------------------
extern "C" void kernel_launch(void* const* d_in, const int* in_sizes, int n_in,
                              void* d_out, int out_size, void* d_ws, size_t ws_size,
                              hipStream_t stream) {
    const float* feat  = (const float*)d_in[0];
    const float* Wq    = (const float*)d_in[1];
    const float* Wk    = (const float*)d_in[2];
    const float* cw    = (const float*)d_in[3];
    const float* cb    = (const float*)d_in[4];
    const float* ls    = (const float*)d_in[5];
    const float* ssp   = (const float*)d_in[6];
    const float* decay = (const float*)d_in[7];

    float* ws     = (float*)d_ws;
    float* base   = ws + BASE_OFF;
    float* Qp     = ws + Q_OFF;
    float* Kp     = ws + K_OFF;
    float* m_arr  = ws + M_OFF;
    float* invs   = ws + S_OFF;
    float* charge = ws + C_OFF;   // 5 x [BN]; slot 0 = initial
    float* recv   = ws + R_OFF;
    float* out    = (float*)d_out;

    // qk partials live in the base region (consumed by qk_reduce before base_kernel)
    float* partQ = base;                        // [4][BN][DE]
    float* partK = base + (size_t)4 * BN * DE;  // [4][BN][DE]

    qk_gemm<<<dim3(BN / 32, 4), 256, 0, stream>>>(feat, Wq, Wk, partQ, partK);
    charge_init<<<BN / 4, 256, 0, stream>>>(feat, cw, cb, charge);
    qk_reduce<<<(BN * DE / 4) / 256, 256, 0, stream>>>(partQ, partK, Qp, Kp);
    base_kernel<<<dim3(NN / 128, NN / 128, NB), 256, 0, stream>>>(Qp, Kp, ls, base);

    for (int t = 0; t < 4; ++t) {
        row_pass<0><<<BN, 256, 0, stream>>>(base, charge, t, ssp, m_arr, invs, recv, nullptr);
        col_pass<<<dim3(NN / 256, NN / 128, NB), 256, 0, stream>>>(
            base, charge, t, ssp, m_arr, invs, recv);
        charge_update<<<BN / 256, 256, 0, stream>>>(
            recv, decay, charge + (size_t)t * BN, charge + (size_t)(t + 1) * BN);
    }
    row_pass<1><<<BN, 256, 0, stream>>>(base, charge, 4, ssp, m_arr, invs, recv, out);
}

// Round 3
// 351.664 us; speedup vs baseline: 1.3609x; 1.2558x over previous
//
#include <hip/hip_runtime.h>
#include <math.h>

namespace {
constexpr int NB = 4;       // batch
constexpr int NN = 2048;    // sequence
constexpr int FD = 1024;    // feature dim
constexpr int DE = 128;     // energy dim
constexpr int BN = NB * NN; // 8192 rows total

// ---- workspace layout (f32 units). Total 18,923,520 f32 = 75.7 MB
// (== round-1 footprint, which the harness accepted).
// Phase A (before base_mfma) overlays inside the base region:
//   [0 .. 4,194,304)        partQ  [4][8192][128] f32
//   [4,194,304 .. 8,388,608) partK
//   [8,388,608 .. 16,777,216) Fh,Fl bf16  (2 x 8,388,608 ushort)
// QKHL region (after base): Qh,Ql,Kh,Kl bf16 (4 x 1,048,576 ushort)
//   overlaid during phase A by Wt: Wqh,Wql,Wkh,Wkl ([e][f] 128x1024 each)
constexpr size_t BASE_OFF = 0;
constexpr size_t PARTQ_OFF = 0;
constexpr size_t PARTK_OFF = 4194304;
constexpr size_t F16_OFF   = 8388608;              // as f32 idx; cast to ushort*
constexpr size_t QKHL_OFF  = 16777216;
constexpr size_t C_OFF     = QKHL_OFF + 2097152;   // 5 x [BN] charges
constexpr size_t R_OFF     = C_OFF + 5 * (size_t)BN;
}

typedef __attribute__((ext_vector_type(8))) short bf16x8;
typedef __attribute__((ext_vector_type(4))) float f32x4;

__device__ __forceinline__ unsigned short bf16_hi(float x) {
    unsigned u = __float_as_uint(x);
    unsigned r = (u + 0x7fffu + ((u >> 16) & 1u)) >> 16;
    return (unsigned short)r;
}
__device__ __forceinline__ float bf16_val(unsigned short h) {
    return __uint_as_float((unsigned)h << 16);
}

// ---------------------------------------------------------------------------
// C1: F fp32 -> Fh, Fl bf16 (split: hi = rn(x), lo = rn(x - hi))
__global__ __launch_bounds__(256) void convert_F(
        const float* __restrict__ feat, unsigned short* __restrict__ Fh,
        unsigned short* __restrict__ Fl) {
    const size_t i4 = ((size_t)blockIdx.x * 256 + threadIdx.x) * 4;
    float4 v = *(const float4*)&feat[i4];
    ushort4 h, l;
    h.x = bf16_hi(v.x); l.x = bf16_hi(v.x - bf16_val(h.x));
    h.y = bf16_hi(v.y); l.y = bf16_hi(v.y - bf16_val(h.y));
    h.z = bf16_hi(v.z); l.z = bf16_hi(v.z - bf16_val(h.z));
    h.w = bf16_hi(v.w); l.w = bf16_hi(v.w - bf16_val(h.w));
    *(ushort4*)&Fh[i4] = h;
    *(ushort4*)&Fl[i4] = l;
}

// ---------------------------------------------------------------------------
// C2: W [f][e] fp32 -> Wt hi/lo [e][f] bf16 (transposed for B-frag loads).
// grid (128, 2): x = e, y = matrix (0=Wq, 1=Wk)
__global__ __launch_bounds__(256) void convert_W(
        const float* __restrict__ Wq, const float* __restrict__ Wk,
        unsigned short* __restrict__ Wqh, unsigned short* __restrict__ Wql,
        unsigned short* __restrict__ Wkh, unsigned short* __restrict__ Wkl) {
    const int e = blockIdx.x;
    const int f0 = threadIdx.x * 4;
    const float* W = blockIdx.y ? Wk : Wq;
    unsigned short* Th = blockIdx.y ? Wkh : Wqh;
    unsigned short* Tl = blockIdx.y ? Wkl : Wql;
    ushort4 h, l;
    float v0 = W[(size_t)(f0 + 0) * DE + e];
    float v1 = W[(size_t)(f0 + 1) * DE + e];
    float v2 = W[(size_t)(f0 + 2) * DE + e];
    float v3 = W[(size_t)(f0 + 3) * DE + e];
    h.x = bf16_hi(v0); l.x = bf16_hi(v0 - bf16_val(h.x));
    h.y = bf16_hi(v1); l.y = bf16_hi(v1 - bf16_val(h.y));
    h.z = bf16_hi(v2); l.z = bf16_hi(v2 - bf16_val(h.z));
    h.w = bf16_hi(v3); l.w = bf16_hi(v3 - bf16_val(h.w));
    *(ushort4*)&Th[(size_t)e * FD + f0] = h;
    *(ushort4*)&Tl[(size_t)e * FD + f0] = l;
}

// ---------------------------------------------------------------------------
// Kc: c0 = sigmoid(F @ cw + cb); also zero received.
__global__ __launch_bounds__(256) void charge_init(
        const float* __restrict__ feat, const float* __restrict__ cw,
        const float* __restrict__ cb, float* __restrict__ c0,
        float* __restrict__ received) {
    const int wave = threadIdx.x >> 6, lane = threadIdx.x & 63;
    const int r = blockIdx.x * 4 + wave;
    const float* fr = feat + (size_t)r * FD;
    float s = 0.f;
    #pragma unroll
    for (int k = 0; k < 16; ++k) { int f = lane + 64 * k; s += fr[f] * cw[f]; }
    for (int off = 32; off > 0; off >>= 1) s += __shfl_xor(s, off);
    if (lane == 0) {
        float x = s + cb[0];
        c0[r] = 1.f / (1.f + __expf(-x));
        received[r] = 0.f;
    }
}

// ---------------------------------------------------------------------------
// K0: split-bf16 MFMA projection. Output partials per 256-f K-chunk.
// grid (4, 128): x = kchunk, y = 64-row block. 4 waves:
//   wave 0/1 -> Q cols [0,64)/[64,128);  wave 2/3 -> K same.
// Each wave: 4 row-tiles x 4 col-tiles of 16x16, K-chunks of 32, 3 MFMAs/product.
__global__ __launch_bounds__(256) void qk_mfma(
        const unsigned short* __restrict__ Fh, const unsigned short* __restrict__ Fl,
        const unsigned short* __restrict__ Wqh, const unsigned short* __restrict__ Wql,
        const unsigned short* __restrict__ Wkh, const unsigned short* __restrict__ Wkl,
        float* __restrict__ partQ, float* __restrict__ partK) {
    const int tid = threadIdx.x;
    const int w = tid >> 6, lane = tid & 63;
    const int quad = lane >> 4, l16 = lane & 15;
    const int kc = blockIdx.x;
    const int r0 = blockIdx.y * 64;
    const unsigned short* Bh = (w < 2) ? Wqh : Wkh;
    const unsigned short* Bl = (w < 2) ? Wql : Wkl;
    const int e0 = (w & 1) * 64;
    float* part = ((w < 2) ? partQ : partK) + (size_t)kc * BN * DE;

    f32x4 acc[4][4];
    #pragma unroll
    for (int a = 0; a < 4; ++a)
        #pragma unroll
        for (int c = 0; c < 4; ++c) acc[a][c] = (f32x4){0.f, 0.f, 0.f, 0.f};

    #pragma unroll 2
    for (int ch = 0; ch < 8; ++ch) {
        const int f = kc * 256 + ch * 32 + quad * 8;
        bf16x8 aH[4], aL[4];
        #pragma unroll
        for (int rt = 0; rt < 4; ++rt) {
            const size_t off = (size_t)(r0 + rt * 16 + l16) * FD + f;
            aH[rt] = *(const bf16x8*)&Fh[off];
            aL[rt] = *(const bf16x8*)&Fl[off];
        }
        #pragma unroll
        for (int ct = 0; ct < 4; ++ct) {
            const size_t off = (size_t)(e0 + ct * 16 + l16) * FD + f;
            bf16x8 bH = *(const bf16x8*)&Bh[off];
            bf16x8 bL = *(const bf16x8*)&Bl[off];
            #pragma unroll
            for (int rt = 0; rt < 4; ++rt) {
                acc[rt][ct] = __builtin_amdgcn_mfma_f32_16x16x32_bf16(aH[rt], bH, acc[rt][ct], 0, 0, 0);
                acc[rt][ct] = __builtin_amdgcn_mfma_f32_16x16x32_bf16(aH[rt], bL, acc[rt][ct], 0, 0, 0);
                acc[rt][ct] = __builtin_amdgcn_mfma_f32_16x16x32_bf16(aL[rt], bH, acc[rt][ct], 0, 0, 0);
            }
        }
    }
    #pragma unroll
    for (int rt = 0; rt < 4; ++rt)
        #pragma unroll
        for (int ct = 0; ct < 4; ++ct)
            #pragma unroll
            for (int reg = 0; reg < 4; ++reg) {
                const int row = r0 + rt * 16 + quad * 4 + reg;
                const int e = e0 + ct * 16 + l16;
                part[(size_t)row * DE + e] = acc[rt][ct][reg];
            }
}

// ---------------------------------------------------------------------------
// R0: sum 4 K-chunk partials, convert straight to bf16 hi/lo Q/K.
__global__ __launch_bounds__(256) void qk_reduce(
        const float* __restrict__ partQ, const float* __restrict__ partK,
        unsigned short* __restrict__ Qh, unsigned short* __restrict__ Ql,
        unsigned short* __restrict__ Kh, unsigned short* __restrict__ Kl) {
    const size_t i4 = ((size_t)blockIdx.x * 256 + threadIdx.x) * 4;
    float4 q = {0.f, 0.f, 0.f, 0.f}, k = {0.f, 0.f, 0.f, 0.f};
    #pragma unroll
    for (int c = 0; c < 4; ++c) {
        float4 a = *(const float4*)&partQ[(size_t)c * BN * DE + i4];
        float4 b = *(const float4*)&partK[(size_t)c * BN * DE + i4];
        q.x += a.x; q.y += a.y; q.z += a.z; q.w += a.w;
        k.x += b.x; k.y += b.y; k.z += b.z; k.w += b.w;
    }
    ushort4 h, l;
    h.x = bf16_hi(q.x); l.x = bf16_hi(q.x - bf16_val(h.x));
    h.y = bf16_hi(q.y); l.y = bf16_hi(q.y - bf16_val(h.y));
    h.z = bf16_hi(q.z); l.z = bf16_hi(q.z - bf16_val(h.z));
    h.w = bf16_hi(q.w); l.w = bf16_hi(q.w - bf16_val(h.w));
    *(ushort4*)&Qh[i4] = h; *(ushort4*)&Ql[i4] = l;
    h.x = bf16_hi(k.x); l.x = bf16_hi(k.x - bf16_val(h.x));
    h.y = bf16_hi(k.y); l.y = bf16_hi(k.y - bf16_val(h.y));
    h.z = bf16_hi(k.z); l.z = bf16_hi(k.z - bf16_val(h.z));
    h.w = bf16_hi(k.w); l.w = bf16_hi(k.w - bf16_val(h.w));
    *(ushort4*)&Kh[i4] = h; *(ushort4*)&Kl[i4] = l;
}

// ---------------------------------------------------------------------------
// K1: base = (Q.K^T)/sqrt(128) + locality, split-bf16 MFMA, no LDS.
// grid (16,16,NB): 128x128 tile. Wave w: rows w*32..w*32+32 (2 row-tiles) x 8 col-tiles.
__global__ __launch_bounds__(256) void base_mfma(
        const unsigned short* __restrict__ Qh, const unsigned short* __restrict__ Ql,
        const unsigned short* __restrict__ Kh, const unsigned short* __restrict__ Kl,
        const float* __restrict__ d_ls, float* __restrict__ base) {
    const int tid = threadIdx.x;
    const int w = tid >> 6, lane = tid & 63;
    const int quad = lane >> 4, l16 = lane & 15;
    const int b = blockIdx.z;
    const int i0 = blockIdx.y * 128, j0 = blockIdx.x * 128;
    const size_t boff = (size_t)b * NN * DE;

    f32x4 acc[2][8];
    #pragma unroll
    for (int a = 0; a < 2; ++a)
        #pragma unroll
        for (int c = 0; c < 8; ++c) acc[a][c] = (f32x4){0.f, 0.f, 0.f, 0.f};

    #pragma unroll
    for (int kc = 0; kc < 4; ++kc) {
        const int kofs = kc * 32 + quad * 8;
        bf16x8 aH[2], aL[2];
        #pragma unroll
        for (int rt = 0; rt < 2; ++rt) {
            const size_t off = boff + (size_t)(i0 + w * 32 + rt * 16 + l16) * DE + kofs;
            aH[rt] = *(const bf16x8*)&Qh[off];
            aL[rt] = *(const bf16x8*)&Ql[off];
        }
        #pragma unroll
        for (int ct = 0; ct < 8; ++ct) {
            const size_t off = boff + (size_t)(j0 + ct * 16 + l16) * DE + kofs;
            bf16x8 bH = *(const bf16x8*)&Kh[off];
            bf16x8 bL = *(const bf16x8*)&Kl[off];
            #pragma unroll
            for (int rt = 0; rt < 2; ++rt) {
                acc[rt][ct] = __builtin_amdgcn_mfma_f32_16x16x32_bf16(aH[rt], bH, acc[rt][ct], 0, 0, 0);
                acc[rt][ct] = __builtin_amdgcn_mfma_f32_16x16x32_bf16(aH[rt], bL, acc[rt][ct], 0, 0, 0);
                acc[rt][ct] = __builtin_amdgcn_mfma_f32_16x16x32_bf16(aL[rt], bH, acc[rt][ct], 0, 0, 0);
            }
        }
    }
    const float ls = d_ls[0];
    const float rs = 0.08838834764831845f;  // 1/sqrt(128)
    #pragma unroll
    for (int rt = 0; rt < 2; ++rt)
        #pragma unroll
        for (int reg = 0; reg < 4; ++reg) {
            const int i = i0 + w * 32 + rt * 16 + quad * 4 + reg;
            float* brow = base + ((size_t)b * NN + i) * NN;
            #pragma unroll
            for (int ct = 0; ct < 8; ++ct) {
                const int j = j0 + ct * 16 + l16;
                const float dist = fmaxf(fabsf((float)(i - j)), 1.0f);
                brow[j] = acc[rt][ct][reg] * rs + ls / dist;
            }
        }
}

// ---------------------------------------------------------------------------
// K2 (fused): per 16-row block: row softmax stats + row of attn; accumulate
// column partials -> received (one atomicAdd per col per block).
// Wave w owns rows rbase + w*4 + (0..3); lane owns 32 cols (8 float4 groups).
template <bool WRITE_OUT>
__global__ __launch_bounds__(256) void step_pass(
        const float* __restrict__ base, const float* __restrict__ charge,
        const int t, const float* __restrict__ d_ss,
        float* __restrict__ received, float* __restrict__ out) {
    __shared__ float colsum[4][NN];
    const int tid = threadIdx.x;
    const int w = tid >> 6, lane = tid & 63;
    const int b = blockIdx.x >> 7;              // 128 blocks per batch
    const int rbase = (blockIdx.x & 127) * 16;
    const float ss = d_ss[0];
    const size_t cb = (size_t)b << 11;          // per-batch column offset

    float col_acc[32];
    #pragma unroll
    for (int q = 0; q < 32; ++q) col_acc[q] = 0.f;

    for (int rr = 0; rr < 4; ++rr) {
        const size_t ri = cb + rbase + w * 4 + rr;
        const float* row = base + ri * NN;
        float ci[4];
        for (int u = 0; u < t; ++u) ci[u] = charge[(size_t)(u + 1) * BN + ri] * ss;

        float x[32];
        float mx = -1e30f;
        #pragma unroll
        for (int k = 0; k < 8; ++k) {
            const int c = k * 256 + lane * 4;
            float4 bv = *(const float4*)&row[c];
            float m0 = 1.f, m1 = 1.f, m2 = 1.f, m3 = 1.f;
            for (int u = 0; u < t; ++u) {
                float4 cj = *(const float4*)&charge[(size_t)(u + 1) * BN + cb + c];
                m0 += ci[u] * cj.x; m1 += ci[u] * cj.y;
                m2 += ci[u] * cj.z; m3 += ci[u] * cj.w;
            }
            x[k * 4 + 0] = bv.x * m0; x[k * 4 + 1] = bv.y * m1;
            x[k * 4 + 2] = bv.z * m2; x[k * 4 + 3] = bv.w * m3;
            mx = fmaxf(mx, fmaxf(fmaxf(x[k * 4], x[k * 4 + 1]),
                                 fmaxf(x[k * 4 + 2], x[k * 4 + 3])));
        }
        #pragma unroll
        for (int off = 32; off > 0; off >>= 1) mx = fmaxf(mx, __shfl_xor(mx, off));

        float se = 0.f;
        #pragma unroll
        for (int q = 0; q < 32; ++q) { x[q] = __expf(x[q] - mx); se += x[q]; }
        #pragma unroll
        for (int off = 32; off > 0; off >>= 1) se += __shfl_xor(se, off);
        const float inv = 1.0f / se;

        if (WRITE_OUT) {
            #pragma unroll
            for (int k = 0; k < 8; ++k) {
                const int c = k * 256 + lane * 4;
                float4 o = {x[k * 4 + 0] * inv, x[k * 4 + 1] * inv,
                            x[k * 4 + 2] * inv, x[k * 4 + 3] * inv};
                *(float4*)&out[ri * NN + c] = o;
            }
        } else {
            #pragma unroll
            for (int q = 0; q < 32; ++q) col_acc[q] += x[q] * inv;
        }
    }

    if (!WRITE_OUT) {
        // wave-private slab (each wave's lanes cover all 2048 cols exactly once)
        #pragma unroll
        for (int k = 0; k < 8; ++k) {
            const int c = k * 256 + lane * 4;
            *(float4*)&colsum[w][c] = *(float4*)&col_acc[k * 4];
        }
        __syncthreads();
        #pragma unroll
        for (int k = 0; k < 8; ++k) {
            const int c = tid + 256 * k;
            const float s = colsum[0][c] + colsum[1][c] + colsum[2][c] + colsum[3][c];
            atomicAdd(&received[cb + c], s);
        }
    }
}

// ---------------------------------------------------------------------------
// K4: c_{t+1} = c_t * (1 - decay * sigmoid(received - 1)); re-zero received.
__global__ __launch_bounds__(256) void charge_update(
        float* __restrict__ received, const float* __restrict__ d_decay,
        const float* __restrict__ c_prev, float* __restrict__ c_next) {
    const int r = blockIdx.x * 256 + threadIdx.x;
    const float recv = received[r];
    received[r] = 0.f;
    const float sg = 1.f / (1.f + __expf(1.f - recv));
    c_next[r] = c_prev[r] * (1.f - d_decay[0] * sg);
}

// ---------------------------------------------------------------------------
extern "C" void kernel_launch(void* const* d_in, const int* in_sizes, int n_in,
                              void* d_out, int out_size, void* d_ws, size_t ws_size,
                              hipStream_t stream) {
    const float* feat  = (const float*)d_in[0];
    const float* Wq    = (const float*)d_in[1];
    const float* Wk    = (const float*)d_in[2];
    const float* cw    = (const float*)d_in[3];
    const float* cb    = (const float*)d_in[4];
    const float* ls    = (const float*)d_in[5];
    const float* ssp   = (const float*)d_in[6];
    const float* decay = (const float*)d_in[7];

    float* ws   = (float*)d_ws;
    float* base = ws + BASE_OFF;
    float* partQ = ws + PARTQ_OFF;
    float* partK = ws + PARTK_OFF;
    unsigned short* Fh = (unsigned short*)(ws + F16_OFF);
    unsigned short* Fl = Fh + (size_t)BN * FD;
    unsigned short* qkhl = (unsigned short*)(ws + QKHL_OFF);
    unsigned short* Qh = qkhl;
    unsigned short* Ql = qkhl + (size_t)BN * DE;
    unsigned short* Kh = qkhl + (size_t)2 * BN * DE;
    unsigned short* Kl = qkhl + (size_t)3 * BN * DE;
    // Wt overlays the QKHL region during phase A (dead before qk_reduce writes it)
    unsigned short* Wqh = qkhl;
    unsigned short* Wql = qkhl + (size_t)DE * FD;
    unsigned short* Wkh = qkhl + (size_t)2 * DE * FD;
    unsigned short* Wkl = qkhl + (size_t)3 * DE * FD;
    float* charge = ws + C_OFF;
    float* recv   = ws + R_OFF;
    float* out    = (float*)d_out;

    convert_F<<<BN * FD / 4 / 256, 256, 0, stream>>>(feat, Fh, Fl);
    convert_W<<<dim3(DE, 2), 256, 0, stream>>>(Wq, Wk, Wqh, Wql, Wkh, Wkl);
    charge_init<<<BN / 4, 256, 0, stream>>>(feat, cw, cb, charge, recv);
    qk_mfma<<<dim3(4, BN / 64), 256, 0, stream>>>(Fh, Fl, Wqh, Wql, Wkh, Wkl, partQ, partK);
    qk_reduce<<<BN * DE / 4 / 256, 256, 0, stream>>>(partQ, partK, Qh, Ql, Kh, Kl);
    base_mfma<<<dim3(NN / 128, NN / 128, NB), 256, 0, stream>>>(Qh, Ql, Kh, Kl, ls, base);

    for (int t = 0; t < 4; ++t) {
        step_pass<false><<<BN / 16, 256, 0, stream>>>(base, charge, t, ssp, recv, nullptr);
        charge_update<<<BN / 256, 256, 0, stream>>>(
            recv, decay, charge + (size_t)t * BN, charge + (size_t)(t + 1) * BN);
    }
    step_pass<true><<<BN / 16, 256, 0, stream>>>(base, charge, 4, ssp, recv, out);
}

// Round 5
// 309.111 us; speedup vs baseline: 1.5482x; 1.1377x over previous
//
#include <hip/hip_runtime.h>
#include <math.h>

namespace {
constexpr int NB = 4;       // batch
constexpr int NN = 2048;    // sequence
constexpr int FD = 1024;    // feature dim
constexpr int DE = 128;     // energy dim
constexpr int BN = NB * NN; // 8192 rows total

// ---- workspace layout (f32 units). Total 18,923,520 f32 = 75.7 MB.
// Phase A overlays inside the base region:
//   [0 .. 4,194,304)          partQ [4][8192][128] f32
//   [4,194,304 .. 8,388,608)  partK
//   [8,388,608 .. 12,582,912) Fh_sw (8.4M ushort, frag-tiled)
//   [12,582,912 .. 16,777,216) Fl_sw
// QKHL region (after base): Qh,Ql,Kh,Kl frag-tiled bf16 (4 x 1,048,576 ushort)
//   overlaid during phase A by Wsw (4 x 131,072 ushort)
constexpr size_t BASE_OFF  = 0;
constexpr size_t PARTQ_OFF = 0;
constexpr size_t PARTK_OFF = 4194304;
constexpr size_t FH_OFF    = 8388608;
constexpr size_t FL_OFF    = 12582912;
constexpr size_t QKHL_OFF  = 16777216;
constexpr size_t C_OFF     = QKHL_OFF + 2097152;   // 5 x [BN] charges
constexpr size_t R_OFF     = C_OFF + 5 * (size_t)BN;
}

typedef __attribute__((ext_vector_type(8))) short bf16x8;
typedef __attribute__((ext_vector_type(4))) float f32x4;

__device__ __forceinline__ unsigned short bf16_hi(float x) {
    unsigned u = __float_as_uint(x);
    unsigned r = (u + 0x7fffu + ((u >> 16) & 1u)) >> 16;
    return (unsigned short)r;
}
__device__ __forceinline__ float bf16_val(unsigned short h) {
    return __uint_as_float((unsigned)h << 16);
}

// Frag-tile layout: tile(row0=16 rows, k0=32 k) -> 64 lanes x 8 bf16, 1KB
// contiguous. lane = quad*16 + l16 holds (row = row0+l16, k = k0+quad*8+j).
// Identical mapping serves both A and B operands of mfma_f32_16x16x32_bf16.

// ---------------------------------------------------------------------------
// C1: F fp32 -> Fh_sw, Fl_sw (split hi/lo, frag-tiled).
// One thread per (tile, lane): reads 8 consecutive f32, writes 16B coalesced.
// NEEDS BN*FD/8 threads (8 f32 per thread) -> 4096 blocks of 256.
__global__ __launch_bounds__(256) void convert_F(
        const float* __restrict__ feat, unsigned short* __restrict__ Fh,
        unsigned short* __restrict__ Fl) {
    const int g = blockIdx.x * 256 + threadIdx.x;
    const int tile = g >> 6, lane = g & 63;
    const int tr = tile >> 5, fc = tile & 31;          // tr: 512 row-tiles, fc: 32 k-tiles
    const int row = tr * 16 + (lane & 15);
    const int f0 = fc * 32 + (lane >> 4) * 8;
    const float* src = &feat[(size_t)row * FD + f0];
    ushort4 h0, l0, h1, l1;
    float4 a = *(const float4*)src;
    float4 b = *(const float4*)(src + 4);
    h0.x = bf16_hi(a.x); l0.x = bf16_hi(a.x - bf16_val(h0.x));
    h0.y = bf16_hi(a.y); l0.y = bf16_hi(a.y - bf16_val(h0.y));
    h0.z = bf16_hi(a.z); l0.z = bf16_hi(a.z - bf16_val(h0.z));
    h0.w = bf16_hi(a.w); l0.w = bf16_hi(a.w - bf16_val(h0.w));
    h1.x = bf16_hi(b.x); l1.x = bf16_hi(b.x - bf16_val(h1.x));
    h1.y = bf16_hi(b.y); l1.y = bf16_hi(b.y - bf16_val(h1.y));
    h1.z = bf16_hi(b.z); l1.z = bf16_hi(b.z - bf16_val(h1.z));
    h1.w = bf16_hi(b.w); l1.w = bf16_hi(b.w - bf16_val(h1.w));
    const size_t dst = (size_t)tile * 512 + lane * 8;
    *(ushort4*)&Fh[dst] = h0; *(ushort4*)&Fh[dst + 4] = h1;
    *(ushort4*)&Fl[dst] = l0; *(ushort4*)&Fl[dst + 4] = l1;
}

// ---------------------------------------------------------------------------
// C2: W [f][e] fp32 -> frag-tiled hi/lo (tile = 16 e x 32 f).
// grid (64, 2): 256 tiles/mat * 64 lanes = 16384 threads/mat.
__global__ __launch_bounds__(256) void convert_W(
        const float* __restrict__ Wq, const float* __restrict__ Wk,
        unsigned short* __restrict__ Wqh, unsigned short* __restrict__ Wql,
        unsigned short* __restrict__ Wkh, unsigned short* __restrict__ Wkl) {
    const int g = blockIdx.x * 256 + threadIdx.x;
    const int tile = g >> 6, lane = g & 63;
    const int ec = tile >> 5, fc = tile & 31;
    const int e = ec * 16 + (lane & 15);
    const int f0 = fc * 32 + (lane >> 4) * 8;
    const float* W = blockIdx.y ? Wk : Wq;
    unsigned short* Th = blockIdx.y ? Wkh : Wqh;
    unsigned short* Tl = blockIdx.y ? Wkl : Wql;
    unsigned short hh[8], ll[8];
    #pragma unroll
    for (int j = 0; j < 8; ++j) {
        float v = W[(size_t)(f0 + j) * DE + e];
        hh[j] = bf16_hi(v); ll[j] = bf16_hi(v - bf16_val(hh[j]));
    }
    const size_t dst = (size_t)tile * 512 + lane * 8;
    *(ushort4*)&Th[dst]     = make_ushort4(hh[0], hh[1], hh[2], hh[3]);
    *(ushort4*)&Th[dst + 4] = make_ushort4(hh[4], hh[5], hh[6], hh[7]);
    *(ushort4*)&Tl[dst]     = make_ushort4(ll[0], ll[1], ll[2], ll[3]);
    *(ushort4*)&Tl[dst + 4] = make_ushort4(ll[4], ll[5], ll[6], ll[7]);
}

// ---------------------------------------------------------------------------
// Kc: c0 = sigmoid(F @ cw + cb); also zero received.
__global__ __launch_bounds__(256) void charge_init(
        const float* __restrict__ feat, const float* __restrict__ cw,
        const float* __restrict__ cb, float* __restrict__ c0,
        float* __restrict__ received) {
    const int wave = threadIdx.x >> 6, lane = threadIdx.x & 63;
    const int r = blockIdx.x * 4 + wave;
    const float* fr = feat + (size_t)r * FD;
    float s = 0.f;
    #pragma unroll
    for (int k = 0; k < 16; ++k) { int f = lane + 64 * k; s += fr[f] * cw[f]; }
    for (int off = 32; off > 0; off >>= 1) s += __shfl_xor(s, off);
    if (lane == 0) {
        float x = s + cb[0];
        c0[r] = 1.f / (1.f + __expf(-x));
        received[r] = 0.f;
    }
}

// ---------------------------------------------------------------------------
// K0: split-bf16 MFMA projection, frag-tiled inputs (all loads coalesced 1KB).
// grid (4, 128): x = 256-f K-chunk, y = 64-row block. Wave w: mat = w>>1,
// e-half = w&1 (4 col-tiles); 4 row-tiles; 3 MFMAs per product.
__global__ __launch_bounds__(256) void qk_mfma(
        const unsigned short* __restrict__ Fh, const unsigned short* __restrict__ Fl,
        const unsigned short* __restrict__ Wqh, const unsigned short* __restrict__ Wql,
        const unsigned short* __restrict__ Wkh, const unsigned short* __restrict__ Wkl,
        float* __restrict__ partQ, float* __restrict__ partK) {
    const int tid = threadIdx.x;
    const int w = tid >> 6, lane = tid & 63;
    const int quad = lane >> 4, l16 = lane & 15;
    const int kc = blockIdx.x;
    const int tr0 = blockIdx.y * 4;             // row-tile base (64 rows)
    const unsigned short* Bh = (w < 2) ? Wqh : Wkh;
    const unsigned short* Bl = (w < 2) ? Wql : Wkl;
    const int ec0 = (w & 1) * 4;
    float* part = ((w < 2) ? partQ : partK) + (size_t)kc * BN * DE;

    f32x4 acc[4][4];
    #pragma unroll
    for (int a = 0; a < 4; ++a)
        #pragma unroll
        for (int c = 0; c < 4; ++c) acc[a][c] = (f32x4){0.f, 0.f, 0.f, 0.f};

    #pragma unroll 2
    for (int ch = 0; ch < 8; ++ch) {
        const int fc = kc * 8 + ch;             // k-tile index (32 f each)
        bf16x8 aH[4], aL[4];
        #pragma unroll
        for (int rt = 0; rt < 4; ++rt) {
            const size_t off = ((size_t)((tr0 + rt) * 32 + fc) * 64 + lane) * 8;
            aH[rt] = *(const bf16x8*)&Fh[off];
            aL[rt] = *(const bf16x8*)&Fl[off];
        }
        #pragma unroll
        for (int ct = 0; ct < 4; ++ct) {
            const size_t off = ((size_t)((ec0 + ct) * 32 + fc) * 64 + lane) * 8;
            bf16x8 bH = *(const bf16x8*)&Bh[off];
            bf16x8 bL = *(const bf16x8*)&Bl[off];
            #pragma unroll
            for (int rt = 0; rt < 4; ++rt) {
                acc[rt][ct] = __builtin_amdgcn_mfma_f32_16x16x32_bf16(aH[rt], bH, acc[rt][ct], 0, 0, 0);
                acc[rt][ct] = __builtin_amdgcn_mfma_f32_16x16x32_bf16(aH[rt], bL, acc[rt][ct], 0, 0, 0);
                acc[rt][ct] = __builtin_amdgcn_mfma_f32_16x16x32_bf16(aL[rt], bH, acc[rt][ct], 0, 0, 0);
            }
        }
    }
    #pragma unroll
    for (int rt = 0; rt < 4; ++rt)
        #pragma unroll
        for (int ct = 0; ct < 4; ++ct)
            #pragma unroll
            for (int reg = 0; reg < 4; ++reg) {
                const int row = (tr0 + rt) * 16 + quad * 4 + reg;
                const int e = (ec0 + ct) * 16 + l16;
                part[(size_t)row * DE + e] = acc[rt][ct][reg];
            }
}

// ---------------------------------------------------------------------------
// R0: sum 4 K-chunk partials, write frag-tiled bf16 hi/lo Q/K (global row tiles).
__global__ __launch_bounds__(256) void qk_reduce(
        const float* __restrict__ partQ, const float* __restrict__ partK,
        unsigned short* __restrict__ Qh, unsigned short* __restrict__ Ql,
        unsigned short* __restrict__ Kh, unsigned short* __restrict__ Kl) {
    const size_t i4 = ((size_t)blockIdx.x * 256 + threadIdx.x) * 4;
    float4 q = {0.f, 0.f, 0.f, 0.f}, k = {0.f, 0.f, 0.f, 0.f};
    #pragma unroll
    for (int c = 0; c < 4; ++c) {
        float4 a = *(const float4*)&partQ[(size_t)c * BN * DE + i4];
        float4 b = *(const float4*)&partK[(size_t)c * BN * DE + i4];
        q.x += a.x; q.y += a.y; q.z += a.z; q.w += a.w;
        k.x += b.x; k.y += b.y; k.z += b.z; k.w += b.w;
    }
    const int row = (int)(i4 >> 7);
    const int k0  = (int)(i4 & 127);
    const int kc = k0 >> 5, quad = (k0 >> 3) & 3, j = k0 & 7;   // j in {0,4}
    const int lane = quad * 16 + (row & 15);
    const size_t dst = ((size_t)((row >> 4) * 4 + kc) * 64 + lane) * 8 + j;
    ushort4 h, l;
    h.x = bf16_hi(q.x); l.x = bf16_hi(q.x - bf16_val(h.x));
    h.y = bf16_hi(q.y); l.y = bf16_hi(q.y - bf16_val(h.y));
    h.z = bf16_hi(q.z); l.z = bf16_hi(q.z - bf16_val(h.z));
    h.w = bf16_hi(q.w); l.w = bf16_hi(q.w - bf16_val(h.w));
    *(ushort4*)&Qh[dst] = h; *(ushort4*)&Ql[dst] = l;
    h.x = bf16_hi(k.x); l.x = bf16_hi(k.x - bf16_val(h.x));
    h.y = bf16_hi(k.y); l.y = bf16_hi(k.y - bf16_val(h.y));
    h.z = bf16_hi(k.z); l.z = bf16_hi(k.z - bf16_val(h.z));
    h.w = bf16_hi(k.w); l.w = bf16_hi(k.w - bf16_val(h.w));
    *(ushort4*)&Kh[dst] = h; *(ushort4*)&Kl[dst] = l;
}

// ---------------------------------------------------------------------------
// K1: base = (Q.K^T)/sqrt(128) + locality. Frag-tiled coalesced loads, no LDS.
// grid (16,16,NB): 128x128 tile. Wave w: 2 row-tiles x 8 col-tiles.
__global__ __launch_bounds__(256) void base_mfma(
        const unsigned short* __restrict__ Qh, const unsigned short* __restrict__ Ql,
        const unsigned short* __restrict__ Kh, const unsigned short* __restrict__ Kl,
        const float* __restrict__ d_ls, float* __restrict__ base) {
    const int tid = threadIdx.x;
    const int w = tid >> 6, lane = tid & 63;
    const int quad = lane >> 4, l16 = lane & 15;
    const int b = blockIdx.z;
    const int i0 = blockIdx.y * 128, j0 = blockIdx.x * 128;
    const int trA0 = (b * NN + i0) / 16 + w * 2;   // global row-tile for A
    const int trB0 = (b * NN + j0) / 16;           // global row-tile for B

    f32x4 acc[2][8];
    #pragma unroll
    for (int a = 0; a < 2; ++a)
        #pragma unroll
        for (int c = 0; c < 8; ++c) acc[a][c] = (f32x4){0.f, 0.f, 0.f, 0.f};

    #pragma unroll
    for (int kc = 0; kc < 4; ++kc) {
        bf16x8 aH[2], aL[2];
        #pragma unroll
        for (int rt = 0; rt < 2; ++rt) {
            const size_t off = ((size_t)((trA0 + rt) * 4 + kc) * 64 + lane) * 8;
            aH[rt] = *(const bf16x8*)&Qh[off];
            aL[rt] = *(const bf16x8*)&Ql[off];
        }
        #pragma unroll
        for (int ct = 0; ct < 8; ++ct) {
            const size_t off = ((size_t)((trB0 + ct) * 4 + kc) * 64 + lane) * 8;
            bf16x8 bH = *(const bf16x8*)&Kh[off];
            bf16x8 bL = *(const bf16x8*)&Kl[off];
            #pragma unroll
            for (int rt = 0; rt < 2; ++rt) {
                acc[rt][ct] = __builtin_amdgcn_mfma_f32_16x16x32_bf16(aH[rt], bH, acc[rt][ct], 0, 0, 0);
                acc[rt][ct] = __builtin_amdgcn_mfma_f32_16x16x32_bf16(aH[rt], bL, acc[rt][ct], 0, 0, 0);
                acc[rt][ct] = __builtin_amdgcn_mfma_f32_16x16x32_bf16(aL[rt], bH, acc[rt][ct], 0, 0, 0);
            }
        }
    }
    const float ls = d_ls[0];
    const float rs = 0.08838834764831845f;  // 1/sqrt(128)
    #pragma unroll
    for (int rt = 0; rt < 2; ++rt)
        #pragma unroll
        for (int reg = 0; reg < 4; ++reg) {
            const int i = i0 + w * 32 + rt * 16 + quad * 4 + reg;
            float* brow = base + ((size_t)b * NN + i) * NN;
            #pragma unroll
            for (int ct = 0; ct < 8; ++ct) {
                const int j = j0 + ct * 16 + l16;
                const float dist = fmaxf(fabsf((float)(i - j)), 1.0f);
                brow[j] = acc[rt][ct][reg] * rs + ls / dist;
            }
        }
}

// ---------------------------------------------------------------------------
// K2 (fused): row softmax stats + column partials -> received.
template <bool WRITE_OUT>
__global__ __launch_bounds__(256) void step_pass(
        const float* __restrict__ base, const float* __restrict__ charge,
        const int t, const float* __restrict__ d_ss,
        float* __restrict__ received, float* __restrict__ out) {
    __shared__ float colsum[4][NN];
    const int tid = threadIdx.x;
    const int w = tid >> 6, lane = tid & 63;
    const int b = blockIdx.x >> 7;              // 128 blocks per batch
    const int rbase = (blockIdx.x & 127) * 16;
    const float ss = d_ss[0];
    const size_t cb = (size_t)b << 11;          // per-batch column offset

    float col_acc[32];
    #pragma unroll
    for (int q = 0; q < 32; ++q) col_acc[q] = 0.f;

    for (int rr = 0; rr < 4; ++rr) {
        const size_t ri = cb + rbase + w * 4 + rr;
        const float* row = base + ri * NN;
        float ci[4];
        for (int u = 0; u < t; ++u) ci[u] = charge[(size_t)(u + 1) * BN + ri] * ss;

        float x[32];
        float mx = -1e30f;
        #pragma unroll
        for (int k = 0; k < 8; ++k) {
            const int c = k * 256 + lane * 4;
            float4 bv = *(const float4*)&row[c];
            float m0 = 1.f, m1 = 1.f, m2 = 1.f, m3 = 1.f;
            for (int u = 0; u < t; ++u) {
                float4 cj = *(const float4*)&charge[(size_t)(u + 1) * BN + cb + c];
                m0 += ci[u] * cj.x; m1 += ci[u] * cj.y;
                m2 += ci[u] * cj.z; m3 += ci[u] * cj.w;
            }
            x[k * 4 + 0] = bv.x * m0; x[k * 4 + 1] = bv.y * m1;
            x[k * 4 + 2] = bv.z * m2; x[k * 4 + 3] = bv.w * m3;
            mx = fmaxf(mx, fmaxf(fmaxf(x[k * 4], x[k * 4 + 1]),
                                 fmaxf(x[k * 4 + 2], x[k * 4 + 3])));
        }
        #pragma unroll
        for (int off = 32; off > 0; off >>= 1) mx = fmaxf(mx, __shfl_xor(mx, off));

        float se = 0.f;
        #pragma unroll
        for (int q = 0; q < 32; ++q) { x[q] = __expf(x[q] - mx); se += x[q]; }
        #pragma unroll
        for (int off = 32; off > 0; off >>= 1) se += __shfl_xor(se, off);
        const float inv = 1.0f / se;

        if (WRITE_OUT) {
            #pragma unroll
            for (int k = 0; k < 8; ++k) {
                const int c = k * 256 + lane * 4;
                float4 o = {x[k * 4 + 0] * inv, x[k * 4 + 1] * inv,
                            x[k * 4 + 2] * inv, x[k * 4 + 3] * inv};
                *(float4*)&out[ri * NN + c] = o;
            }
        } else {
            #pragma unroll
            for (int q = 0; q < 32; ++q) col_acc[q] += x[q] * inv;
        }
    }

    if (!WRITE_OUT) {
        #pragma unroll
        for (int k = 0; k < 8; ++k) {
            const int c = k * 256 + lane * 4;
            *(float4*)&colsum[w][c] = *(float4*)&col_acc[k * 4];
        }
        __syncthreads();
        #pragma unroll
        for (int k = 0; k < 8; ++k) {
            const int c = tid + 256 * k;
            const float s = colsum[0][c] + colsum[1][c] + colsum[2][c] + colsum[3][c];
            atomicAdd(&received[cb + c], s);
        }
    }
}

// ---------------------------------------------------------------------------
// K4: c_{t+1} = c_t * (1 - decay * sigmoid(received - 1)); re-zero received.
__global__ __launch_bounds__(256) void charge_update(
        float* __restrict__ received, const float* __restrict__ d_decay,
        const float* __restrict__ c_prev, float* __restrict__ c_next) {
    const int r = blockIdx.x * 256 + threadIdx.x;
    const float recv = received[r];
    received[r] = 0.f;
    const float sg = 1.f / (1.f + __expf(1.f - recv));
    c_next[r] = c_prev[r] * (1.f - d_decay[0] * sg);
}

// ---------------------------------------------------------------------------
extern "C" void kernel_launch(void* const* d_in, const int* in_sizes, int n_in,
                              void* d_out, int out_size, void* d_ws, size_t ws_size,
                              hipStream_t stream) {
    const float* feat  = (const float*)d_in[0];
    const float* Wq    = (const float*)d_in[1];
    const float* Wk    = (const float*)d_in[2];
    const float* cw    = (const float*)d_in[3];
    const float* cb    = (const float*)d_in[4];
    const float* ls    = (const float*)d_in[5];
    const float* ssp   = (const float*)d_in[6];
    const float* decay = (const float*)d_in[7];

    float* ws   = (float*)d_ws;
    float* base = ws + BASE_OFF;
    float* partQ = ws + PARTQ_OFF;
    float* partK = ws + PARTK_OFF;
    unsigned short* Fh = (unsigned short*)(ws + FH_OFF);
    unsigned short* Fl = (unsigned short*)(ws + FL_OFF);
    unsigned short* qkhl = (unsigned short*)(ws + QKHL_OFF);
    unsigned short* Qh = qkhl;
    unsigned short* Ql = qkhl + (size_t)BN * DE;
    unsigned short* Kh = qkhl + (size_t)2 * BN * DE;
    unsigned short* Kl = qkhl + (size_t)3 * BN * DE;
    // Wsw overlays the QKHL region during phase A (dead before qk_reduce writes)
    unsigned short* Wqh = qkhl;
    unsigned short* Wql = qkhl + (size_t)DE * FD;
    unsigned short* Wkh = qkhl + (size_t)2 * DE * FD;
    unsigned short* Wkl = qkhl + (size_t)3 * DE * FD;
    float* charge = ws + C_OFF;
    float* recv   = ws + R_OFF;
    float* out    = (float*)d_out;

    // convert_F: one thread per 8 f32 -> BN*FD/8/256 = 4096 blocks (r4 bug: was /64)
    convert_F<<<BN * FD / 8 / 256, 256, 0, stream>>>(feat, Fh, Fl);
    convert_W<<<dim3(64, 2), 256, 0, stream>>>(Wq, Wk, Wqh, Wql, Wkh, Wkl);
    charge_init<<<BN / 4, 256, 0, stream>>>(feat, cw, cb, charge, recv);
    qk_mfma<<<dim3(4, BN / 64), 256, 0, stream>>>(Fh, Fl, Wqh, Wql, Wkh, Wkl, partQ, partK);
    qk_reduce<<<BN * DE / 4 / 256, 256, 0, stream>>>(partQ, partK, Qh, Ql, Kh, Kl);
    base_mfma<<<dim3(NN / 128, NN / 128, NB), 256, 0, stream>>>(Qh, Ql, Kh, Kl, ls, base);

    for (int t = 0; t < 4; ++t) {
        step_pass<false><<<BN / 16, 256, 0, stream>>>(base, charge, t, ssp, recv, nullptr);
        charge_update<<<BN / 256, 256, 0, stream>>>(
            recv, decay, charge + (size_t)t * BN, charge + (size_t)(t + 1) * BN);
    }
    step_pass<true><<<BN / 16, 256, 0, stream>>>(base, charge, 4, ssp, recv, out);
}